// Round 19
// baseline (148.267 us; speedup 1.0000x reference)
//
#include <hip/hip_runtime.h>

#define S 512
#define Dm 512

// ===== PROBE ROUND: all grids are 4x-cloned (blk = blockIdx % real_grid). =====
// Clones recompute and rewrite identical values (idempotent, deterministic).
// Next round restores 1x grids once per-kernel durations are known.

typedef __bf16 bf16x8 __attribute__((ext_vector_type(8)));
typedef float f32x4 __attribute__((ext_vector_type(4)));

// ---------------- bf16 MFMA GEMM with inline fp32->bf16 conversion ----------------
template<bool A_BF16, bool TRANSQK, int REALGRID>
__global__ __launch_bounds__(256) void gemm_icvt(
    const void* __restrict__ Aptr,
    const float* __restrict__ W0, const float* __restrict__ W1, const float* __restrict__ W2,
    const float* __restrict__ b0, const float* __restrict__ b1, const float* __restrict__ b2,
    float* __restrict__ O0, float* __restrict__ O1, float* __restrict__ O2)
{
    int blk = blockIdx.x % REALGRID;
    int m = blk >> 8;
    int tile = blk & 255;
    const float* W = (m == 0) ? W0 : (m == 1) ? W1 : W2;
    const float* bias = (m == 0) ? b0 : (m == 1) ? b1 : b2;
    float* O = (m == 0) ? O0 : (m == 1) ? O1 : O2;
    int rt = tile >> 4, ct = tile & 15;

    int u = threadIdx.x;
    int w = u >> 6, lane = u & 63;
    int r = lane & 15, kg = lane >> 4;

    int row0 = (rt << 5) + ((w >> 1) << 4);
    int col0 = (ct << 5) + ((w & 1) << 4);

    const float* Bp = W + (kg << 3) * Dm + col0 + r;

    f32x4 acc = {0.f, 0.f, 0.f, 0.f};

    #pragma unroll 4
    for (int k0 = 0; k0 < Dm; k0 += 32) {
        bf16x8 a;
        if constexpr (A_BF16) {
            const __bf16* Ab = (const __bf16*)Aptr;
            a = *(const bf16x8*)(Ab + (row0 + r) * Dm + k0 + (kg << 3));
        } else {
            const float* Af = (const float*)Aptr;
            float4 a0 = *(const float4*)(Af + (row0 + r) * Dm + k0 + (kg << 3));
            float4 a1 = *(const float4*)(Af + (row0 + r) * Dm + k0 + (kg << 3) + 4);
            a[0] = (__bf16)a0.x; a[1] = (__bf16)a0.y; a[2] = (__bf16)a0.z; a[3] = (__bf16)a0.w;
            a[4] = (__bf16)a1.x; a[5] = (__bf16)a1.y; a[6] = (__bf16)a1.z; a[7] = (__bf16)a1.w;
        }
        bf16x8 b;
        #pragma unroll
        for (int t = 0; t < 8; ++t)
            b[t] = (__bf16)Bp[(k0 + t) * Dm];
        acc = __builtin_amdgcn_mfma_f32_16x16x32_bf16(a, b, acc, 0, 0, 0);
    }

    int orow = row0 + (kg << 2);
    float bb = bias[col0 + r];

    if constexpr (TRANSQK) {
        if (m < 2) {
            float4 o = make_float4(acc[0] + bb, acc[1] + bb, acc[2] + bb, acc[3] + bb);
            *(float4*)(O + (col0 + r) * S + orow) = o;
            return;
        }
    }
    #pragma unroll
    for (int t = 0; t < 4; ++t)
        O[(orow + t) * Dm + col0 + r] = acc[t] + bb;
}

// ---------------- z-pass, ctx-shaped (r18) ----------------
__global__ __launch_bounds__(512) void zT_kernel(
    const float* __restrict__ QT, const float* __restrict__ KT,
    const float* __restrict__ mask, const float* __restrict__ gamma,
    const float* __restrict__ alpha,
    float* __restrict__ zp, float* __restrict__ Zpart)
{
    int blk = blockIdx.x & 511;        // 4x clone mask
    int h  = blk >> 6;
    int it = blk & 63;
    int i0 = it << 3;
    int c0 = h << 6;

    int u = threadIdx.x;
    int w = u >> 6, lane = u & 63;
    int jj = (w << 6) + lane;

    const float* kcol = KT + (c0 * S) + jj;
    const float* qrow = QT + (c0 * S) + i0;

    float acc[8] = {};
    #pragma unroll 4
    for (int d = 0; d < 64; ++d) {
        float kv = kcol[d * S];
        float4 qa = *(const float4*)(qrow + d * S);
        float4 qb = *(const float4*)(qrow + d * S + 4);
        acc[0] += fabsf(qa.x - kv);
        acc[1] += fabsf(qa.y - kv);
        acc[2] += fabsf(qa.z - kv);
        acc[3] += fabsf(qa.w - kv);
        acc[4] += fabsf(qb.x - kv);
        acc[5] += fabsf(qb.y - kv);
        acc[6] += fabsf(qb.z - kv);
        acc[7] += fabsf(qb.w - kv);
    }

    float sc = 1.0f / (gamma[0] * 8.0f);
    float al = alpha[0];
    float madd = (1.0f - mask[jj]) * 1e6f;

    float zpv[8];
    #pragma unroll
    for (int r = 0; r < 8; ++r) {
        zpv[r] = fmaxf(acc[r] * sc - al, 0.0f) + madd;
        zp[((h << 9) + i0 + r) * S + jj] = zpv[r];
    }

    #pragma unroll
    for (int r = 0; r < 8; ++r) {
        float v = zpv[r];
        v += __shfl_xor(v, 1, 64);
        v += __shfl_xor(v, 2, 64);
        v += __shfl_xor(v, 4, 64);
        v += __shfl_xor(v, 8, 64);
        v += __shfl_xor(v, 16, 64);
        v += __shfl_xor(v, 32, 64);
        zpv[r] = v;
    }
    if (lane == 0) {
        #pragma unroll
        for (int r = 0; r < 8; ++r)
            Zpart[((h << 9) + i0 + r) * 8 + w] = zpv[r];
    }
}

// ---------------- ctx (r8/r16) ----------------
__global__ __launch_bounds__(512) void ctx_kernel(
    const float* __restrict__ V, const float* __restrict__ zp,
    const float* __restrict__ Zpart, __bf16* __restrict__ ctxb)
{
    int blk = blockIdx.x & 511;        // 4x clone mask
    int h = blk >> 6;
    int it = blk & 63;
    int i0 = it << 3;
    int c0 = h << 6;
    int u = threadIdx.x;
    int w = u >> 6, lane = u & 63;

    __shared__ float part[8][8][64];

    int wu = __builtin_amdgcn_readfirstlane(w);
    float acc[8][4] = {};

    #pragma unroll
    for (int cch = 0; cch < 4; ++cch) {
        int jg = (cch << 7) + (wu << 4);
        float vv[16];
        #pragma unroll
        for (int t = 0; t < 16; ++t)
            vv[t] = V[(jg + t) * Dm + c0 + lane];

        const float* zbase = zp + ((h << 9) + i0) * S + jg;
        #pragma unroll
        for (int ii = 0; ii < 8; ++ii) {
            const float* zrow = zbase + ii * S;
            #pragma unroll
            for (int q4 = 0; q4 < 4; ++q4) {
                float4 z4 = *(const float4*)(zrow + (q4 << 2));
                acc[ii][0] += fmaxf(vv[(q4 << 2) + 0], z4.x);
                acc[ii][1] += fmaxf(vv[(q4 << 2) + 1], z4.y);
                acc[ii][2] += fmaxf(vv[(q4 << 2) + 2], z4.z);
                acc[ii][3] += fmaxf(vv[(q4 << 2) + 3], z4.w);
            }
        }
    }

    #pragma unroll
    for (int ii = 0; ii < 8; ++ii)
        part[w][ii][lane] = (acc[ii][0] + acc[ii][1]) + (acc[ii][2] + acc[ii][3]);
    __syncthreads();
    {
        int ii = u >> 6;
        float s = 0.f;
        #pragma unroll
        for (int ww = 0; ww < 8; ++ww) s += part[ww][ii][lane];
        float zsum = 0.f;
        const float* zpr = Zpart + ((h << 9) + (i0 + ii)) * 8;
        #pragma unroll
        for (int p = 0; p < 8; ++p) zsum += zpr[p];
        ctxb[(i0 + ii) * Dm + c0 + lane] = (__bf16)(s - zsum);
    }
}

extern "C" void kernel_launch(void* const* d_in, const int* in_sizes, int n_in,
                              void* d_out, int out_size, void* d_ws, size_t ws_size,
                              hipStream_t stream) {
    const float* hs    = (const float*)d_in[0];
    const float* mask  = (const float*)d_in[1];
    const float* Wq    = (const float*)d_in[2];
    const float* bq    = (const float*)d_in[3];
    const float* Wk    = (const float*)d_in[4];
    const float* bk    = (const float*)d_in[5];
    const float* Wv    = (const float*)d_in[6];
    const float* bv    = (const float*)d_in[7];
    const float* Wo    = (const float*)d_in[8];
    const float* bo    = (const float*)d_in[9];
    const float* gamma = (const float*)d_in[10];
    const float* alpha = (const float*)d_in[11];
    float* out = (float*)d_out;

    char* base = (char*)d_ws;
    float*  zp    = (float*)(base);                               // 8 MB
    float*  Zpart = (float*)(base + (8u << 20));                  // 128 KB
    float*  QT    = (float*)(base + (8u << 20) + (128u << 10));   // 1 MB
    float*  KT    = QT + S * Dm;                                  // 1 MB
    float*  Vb    = KT + S * Dm;                                  // 1 MB
    __bf16* Cbf   = (__bf16*)(Vb + S * Dm);                       // 0.5 MB

    // 4x-cloned grids (probe): 3072 = 4*768, 2048 = 4*512, 1024 = 4*256
    hipLaunchKernelGGL((gemm_icvt<false, true, 768>), dim3(3072), dim3(256), 0, stream,
                       (const void*)hs, Wq, Wk, Wv, bq, bk, bv, QT, KT, Vb);
    hipLaunchKernelGGL(zT_kernel, dim3(2048), dim3(512), 0, stream,
                       QT, KT, mask, gamma, alpha, zp, Zpart);
    hipLaunchKernelGGL(ctx_kernel, dim3(2048), dim3(512), 0, stream,
                       Vb, zp, Zpart, Cbf);
    hipLaunchKernelGGL((gemm_icvt<true, false, 256>), dim3(1024), dim3(256), 0, stream,
                       (const void*)Cbf, Wo, Wo, Wo, bo, bo, bo, out, out, out);
}

// Round 20
// 54.190 us; speedup vs baseline: 2.7361x; 2.7361x over previous
//
#include <hip/hip_runtime.h>

#define S 512
#define Dm 512

typedef __bf16 bf16x8 __attribute__((ext_vector_type(8)));
typedef float f32x4 __attribute__((ext_vector_type(4)));

// ---------------- prep: hs->bf16 (blocks 0..127) ; W->WT bf16 (blocks 128..383) ----------------
__global__ __launch_bounds__(256) void prep_kernel(
    const float* __restrict__ hs,
    const float* __restrict__ W0, const float* __restrict__ W1,
    const float* __restrict__ W2, const float* __restrict__ W3,
    __bf16* __restrict__ Abf,
    __bf16* __restrict__ T0, __bf16* __restrict__ T1,
    __bf16* __restrict__ T2, __bf16* __restrict__ T3)
{
    __shared__ __bf16 Tl[64][72];
    int u = threadIdx.x;
    if (blockIdx.x < 128) {
        int i = (blockIdx.x * 256 + u) * 8;
        float4 x0 = *(const float4*)(hs + i);
        float4 x1 = *(const float4*)(hs + i + 4);
        bf16x8 y;
        y[0] = (__bf16)x0.x; y[1] = (__bf16)x0.y; y[2] = (__bf16)x0.z; y[3] = (__bf16)x0.w;
        y[4] = (__bf16)x1.x; y[5] = (__bf16)x1.y; y[6] = (__bf16)x1.z; y[7] = (__bf16)x1.w;
        *(bf16x8*)(Abf + i) = y;
        return;
    }
    int blk = blockIdx.x - 128;
    int m = blk >> 6;
    int t = blk & 63;
    const float* W = (m == 0) ? W0 : (m == 1) ? W1 : (m == 2) ? W2 : W3;
    __bf16* T = (m == 0) ? T0 : (m == 1) ? T1 : (m == 2) ? T2 : T3;
    int k0 = (t >> 3) << 6;
    int n0 = (t & 7) << 6;
    {
        int kk = u >> 4;
        int n4 = (u & 15) << 2;
        #pragma unroll
        for (int p = 0; p < 4; ++p) {
            int k = kk + (p << 4);
            float4 wv = *(const float4*)(W + (k0 + k) * Dm + n0 + n4);
            Tl[n4 + 0][k] = (__bf16)wv.x;
            Tl[n4 + 1][k] = (__bf16)wv.y;
            Tl[n4 + 2][k] = (__bf16)wv.z;
            Tl[n4 + 3][k] = (__bf16)wv.w;
        }
    }
    __syncthreads();
    {
        int n = u >> 2;
        int ks = (u & 3) << 4;
        uint4 d0 = *(const uint4*)&Tl[n][ks];
        uint4 d1 = *(const uint4*)&Tl[n][ks + 8];
        *(uint4*)(T + (n0 + n) * Dm + k0 + ks) = d0;
        *(uint4*)(T + (n0 + n) * Dm + k0 + ks + 8) = d1;
    }
}

// ---------------- bf16 MFMA GEMM, contiguous bf16 fragments ----------------
// 32x32 tile, 256 thr = 2x2 waves of one 16x16 MFMA. A bf16 [S][Dm], B = WT bf16 [N][K].
// TRANSQK: matrices m<2 written transposed (O^T[col][row]) for the z-pass.
template<bool TRANSQK>
__global__ __launch_bounds__(256) void gemm_bf(
    const __bf16* __restrict__ Abf,
    const __bf16* __restrict__ T0, const __bf16* __restrict__ T1, const __bf16* __restrict__ T2,
    const float* __restrict__ b0, const float* __restrict__ b1, const float* __restrict__ b2,
    float* __restrict__ O0, float* __restrict__ O1, float* __restrict__ O2)
{
    int blk = blockIdx.x;
    int m = blk >> 8;
    int tile = blk & 255;
    const __bf16* T = (m == 0) ? T0 : (m == 1) ? T1 : T2;
    const float* bias = (m == 0) ? b0 : (m == 1) ? b1 : b2;
    float* O = (m == 0) ? O0 : (m == 1) ? O1 : O2;
    int rt = tile >> 4, ct = tile & 15;

    int u = threadIdx.x;
    int w = u >> 6, lane = u & 63;
    int r = lane & 15, kg = lane >> 4;

    int row0 = (rt << 5) + ((w >> 1) << 4);
    int col0 = (ct << 5) + ((w & 1) << 4);

    const __bf16* Ap = Abf + (row0 + r) * Dm + (kg << 3);
    const __bf16* Bp = T + (col0 + r) * Dm + (kg << 3);

    f32x4 acc = {0.f, 0.f, 0.f, 0.f};

    #pragma unroll 4
    for (int k0 = 0; k0 < Dm; k0 += 32) {
        bf16x8 a = *(const bf16x8*)(Ap + k0);
        bf16x8 b = *(const bf16x8*)(Bp + k0);
        acc = __builtin_amdgcn_mfma_f32_16x16x32_bf16(a, b, acc, 0, 0, 0);
    }

    int orow = row0 + (kg << 2);
    float bb = bias[col0 + r];

    if constexpr (TRANSQK) {
        if (m < 2) {
            float4 o = make_float4(acc[0] + bb, acc[1] + bb, acc[2] + bb, acc[3] + bb);
            *(float4*)(O + (col0 + r) * S + orow) = o;
            return;
        }
    }
    #pragma unroll
    for (int t = 0; t < 4; ++t)
        O[(orow + t) * Dm + col0 + r] = acc[t] + bb;
}

// ---------------- fused z' + ctx: block (h,it) owns 8 i-rows x all 512 j ----------------
// grid 512 = 8 heads * 64 i-tiles(8 rows). 512 thr = 8 waves.
// Phase A (zT dataflow): thread j = w*64+lane; KT col coalesced, QT rows scalar;
//   z' -> zs[8][512] LDS (conflict-free), Zsum partials via butterfly -> zpart LDS.
// Phase B (ctx dataflow): wave j-slices, vv per-lane V, z' uniform LDS float4 (broadcast);
//   cross-wave reduce, ctx = sum - Zsum, bf16 out. No zp global round-trip.
__global__ __launch_bounds__(512) void zctx_kernel(
    const float* __restrict__ QT, const float* __restrict__ KT, const float* __restrict__ V,
    const float* __restrict__ mask, const float* __restrict__ gamma,
    const float* __restrict__ alpha, __bf16* __restrict__ ctxb)
{
    int blk = blockIdx.x;
    int h  = blk >> 6;
    int it = blk & 63;
    int i0 = it << 3;
    int c0 = h << 6;

    int u = threadIdx.x;
    int w = u >> 6, lane = u & 63;
    int jj = (w << 6) + lane;

    __shared__ float zs[8][512];       // 16 KB z' tile
    __shared__ float zpart[8][8];      // [wave][row] Zsum partials
    __shared__ float part[8][8][64];   // 16 KB cross-wave reduce

    // ---- phase A: z' ----
    const float* kcol = KT + (c0 * S) + jj;
    const float* qrow = QT + (c0 * S) + i0;

    float acc[8] = {};
    #pragma unroll 4
    for (int d = 0; d < 64; ++d) {
        float kv = kcol[d * S];
        float4 qa = *(const float4*)(qrow + d * S);
        float4 qb = *(const float4*)(qrow + d * S + 4);
        acc[0] += fabsf(qa.x - kv);
        acc[1] += fabsf(qa.y - kv);
        acc[2] += fabsf(qa.z - kv);
        acc[3] += fabsf(qa.w - kv);
        acc[4] += fabsf(qb.x - kv);
        acc[5] += fabsf(qb.y - kv);
        acc[6] += fabsf(qb.z - kv);
        acc[7] += fabsf(qb.w - kv);
    }

    float sc = 1.0f / (gamma[0] * 8.0f);
    float al = alpha[0];
    float madd = (1.0f - mask[jj]) * 1e6f;

    float zpv[8];
    #pragma unroll
    for (int r = 0; r < 8; ++r) {
        zpv[r] = fmaxf(acc[r] * sc - al, 0.0f) + madd;
        zs[r][jj] = zpv[r];            // lanes consecutive -> conflict-free
    }

    #pragma unroll
    for (int r = 0; r < 8; ++r) {
        float v = zpv[r];
        v += __shfl_xor(v, 1, 64);
        v += __shfl_xor(v, 2, 64);
        v += __shfl_xor(v, 4, 64);
        v += __shfl_xor(v, 8, 64);
        v += __shfl_xor(v, 16, 64);
        v += __shfl_xor(v, 32, 64);
        zpv[r] = v;
    }
    if (lane == 0) {
        #pragma unroll
        for (int r = 0; r < 8; ++r) zpart[w][r] = zpv[r];
    }
    __syncthreads();

    // ---- phase B: ctx ----
    int wu = __builtin_amdgcn_readfirstlane(w);
    float a2[8][4] = {};

    #pragma unroll
    for (int cch = 0; cch < 4; ++cch) {
        int jg = (cch << 7) + (wu << 4);
        float vv[16];
        #pragma unroll
        for (int t = 0; t < 16; ++t)
            vv[t] = V[(jg + t) * Dm + c0 + lane];          // per-lane coalesced

        #pragma unroll
        for (int ii = 0; ii < 8; ++ii) {
            #pragma unroll
            for (int q4 = 0; q4 < 4; ++q4) {
                float4 z4 = *(const float4*)&zs[ii][jg + (q4 << 2)];  // uniform -> broadcast
                a2[ii][0] += fmaxf(vv[(q4 << 2) + 0], z4.x);
                a2[ii][1] += fmaxf(vv[(q4 << 2) + 1], z4.y);
                a2[ii][2] += fmaxf(vv[(q4 << 2) + 2], z4.z);
                a2[ii][3] += fmaxf(vv[(q4 << 2) + 3], z4.w);
            }
        }
    }

    #pragma unroll
    for (int ii = 0; ii < 8; ++ii)
        part[w][ii][lane] = (a2[ii][0] + a2[ii][1]) + (a2[ii][2] + a2[ii][3]);
    __syncthreads();

    {
        int ii = u >> 6;
        float s = 0.f;
        #pragma unroll
        for (int ww = 0; ww < 8; ++ww) s += part[ww][ii][lane];
        float zsum = 0.f;
        #pragma unroll
        for (int p = 0; p < 8; ++p) zsum += zpart[p][ii];
        ctxb[(i0 + ii) * Dm + c0 + lane] = (__bf16)(s - zsum);
    }
}

extern "C" void kernel_launch(void* const* d_in, const int* in_sizes, int n_in,
                              void* d_out, int out_size, void* d_ws, size_t ws_size,
                              hipStream_t stream) {
    const float* hs    = (const float*)d_in[0];
    const float* mask  = (const float*)d_in[1];
    const float* Wq    = (const float*)d_in[2];
    const float* bq    = (const float*)d_in[3];
    const float* Wk    = (const float*)d_in[4];
    const float* bk    = (const float*)d_in[5];
    const float* Wv    = (const float*)d_in[6];
    const float* bv    = (const float*)d_in[7];
    const float* Wo    = (const float*)d_in[8];
    const float* bo    = (const float*)d_in[9];
    const float* gamma = (const float*)d_in[10];
    const float* alpha = (const float*)d_in[11];
    float* out = (float*)d_out;

    char* base = (char*)d_ws;
    float*  QT  = (float*)(base);                      // 1 MB (transposed)
    float*  KT  = QT + S * Dm;                         // 1 MB (transposed)
    float*  Vb  = KT + S * Dm;                         // 1 MB
    __bf16* Abf = (__bf16*)(Vb + S * Dm);              // 0.5 MB
    __bf16* T0  = Abf + S * Dm;                        // 0.5 MB each
    __bf16* T1  = T0 + S * Dm;
    __bf16* T2  = T1 + S * Dm;
    __bf16* T3  = T2 + S * Dm;
    __bf16* Cbf = T3 + S * Dm;                         // 0.5 MB

    hipLaunchKernelGGL(prep_kernel, dim3(384), dim3(256), 0, stream,
                       hs, Wq, Wk, Wv, Wo, Abf, T0, T1, T2, T3);
    hipLaunchKernelGGL((gemm_bf<true>), dim3(768), dim3(256), 0, stream,
                       Abf, T0, T1, T2, bq, bk, bv, QT, KT, Vb);
    hipLaunchKernelGGL(zctx_kernel, dim3(512), dim3(512), 0, stream,
                       QT, KT, Vb, mask, gamma, alpha, Cbf);
    hipLaunchKernelGGL((gemm_bf<false>), dim3(256), dim3(256), 0, stream,
                       Cbf, T3, T3, T3, bo, bo, bo, out, out, out);
}